// Round 1
// baseline (150.760 us; speedup 1.0000x reference)
//
#include <hip/hip_runtime.h>
#include <math.h>

// Problem constants (from reference): N=100000, B=4096, S=32, F=E=256
#define S_NEI 32

// ---------------- transpose 256x256 (WkT[e][f] = Wk[f][e]) ----------------
__global__ __launch_bounds__(256) void transpose256(const float* __restrict__ in,
                                                    float* __restrict__ outT) {
    __shared__ float tile[32][33];
    const int bx = blockIdx.x * 32, by = blockIdx.y * 32;
    const int x = threadIdx.x, y = threadIdx.y;  // 32 x 8
#pragma unroll
    for (int i = 0; i < 32; i += 8)
        tile[y + i][x] = in[(by + y + i) * 256 + bx + x];
    __syncthreads();
#pragma unroll
    for (int i = 0; i < 32; i += 8)
        outT[(bx + y + i) * 256 + by + x] = tile[x][y + i];
}

// ---------------- generic 16x256 tile GEMM (256 threads, 4x4/thread) ------
// C tile rows [row0, row0+16), cols [0,256). A row optionally gathered.
template <int KT>
__device__ __forceinline__ void gemm_tile(const float* __restrict__ A,
                                          const int* __restrict__ rowidx, int row0,
                                          int lda, const float* __restrict__ B,
                                          float acc[4][4], float* __restrict__ sA,
                                          float* __restrict__ sB) {
    const int t = threadIdx.x;
    const int tr = t >> 6, tc = t & 63;
    const int r1 = t >> 5;      // 0..7
    const int k1 = t & 31;      // 0..31
    const int r2 = r1 + 8;
    const int arow1 = (rowidx ? rowidx[row0 + r1] : (row0 + r1)) * lda;
    const int arow2 = (rowidx ? rowidx[row0 + r2] : (row0 + r2)) * lda;
    for (int kb = 0; kb < KT; kb += 32) {
        sA[k1 * 17 + r1] = A[arow1 + kb + k1];
        sA[k1 * 17 + r2] = A[arow2 + kb + k1];
#pragma unroll
        for (int i = 0; i < 32; ++i) sB[i * 256 + t] = B[(kb + i) * 256 + t];
        __syncthreads();
#pragma unroll
        for (int k = 0; k < 32; ++k) {
            const float a0 = sA[k * 17 + tr * 4 + 0];
            const float a1 = sA[k * 17 + tr * 4 + 1];
            const float a2 = sA[k * 17 + tr * 4 + 2];
            const float a3 = sA[k * 17 + tr * 4 + 3];
            const float4 b4 = *reinterpret_cast<const float4*>(&sB[k * 256 + tc * 4]);
            acc[0][0] += a0 * b4.x; acc[0][1] += a0 * b4.y; acc[0][2] += a0 * b4.z; acc[0][3] += a0 * b4.w;
            acc[1][0] += a1 * b4.x; acc[1][1] += a1 * b4.y; acc[1][2] += a1 * b4.z; acc[1][3] += a1 * b4.w;
            acc[2][0] += a2 * b4.x; acc[2][1] += a2 * b4.y; acc[2][2] += a2 * b4.z; acc[2][3] += a2 * b4.w;
            acc[3][0] += a3 * b4.x; acc[3][1] += a3 * b4.y; acc[3][2] += a3 * b4.z; acc[3][3] += a3 * b4.w;
        }
        __syncthreads();
    }
}

// ---------------- fused weight products: Wqk=Wq@WkT, Wvc=Wv@Wc_top, Wmc=Wm@Wc_bot
__global__ __launch_bounds__(256) void precompute3(const float* __restrict__ Wq,
                                                   const float* __restrict__ Wv,
                                                   const float* __restrict__ Wm,
                                                   const float* __restrict__ Wc,
                                                   const float* __restrict__ WkT,
                                                   float* __restrict__ Wqk,
                                                   float* __restrict__ Wvc,
                                                   float* __restrict__ Wmc) {
    __shared__ float sA[32 * 17];
    __shared__ float sB[32 * 256];
    float acc[4][4] = {};
    const float *Ap, *Bp;
    float* Cp;
    switch (blockIdx.y) {
        case 0: Ap = Wq; Bp = WkT; Cp = Wqk; break;
        case 1: Ap = Wv; Bp = Wc; Cp = Wvc; break;
        default: Ap = Wm; Bp = Wc + 256 * 256; Cp = Wmc; break;
    }
    const int row0 = blockIdx.x * 16;
    gemm_tile<256>(Ap, nullptr, row0, 256, Bp, acc, sA, sB);
    const int tr = threadIdx.x >> 6, tc = threadIdx.x & 63;
#pragma unroll
    for (int i = 0; i < 4; ++i) {
        float4 v = make_float4(acc[i][0], acc[i][1], acc[i][2], acc[i][3]);
        *reinterpret_cast<float4*>(&Cp[(row0 + tr * 4 + i) * 256 + tc * 4]) = v;
    }
}

// ---------------- fused biases: bqk = bq@WkT ; bfull = bv@Wc_top + bm@Wc_bot + bc
__global__ __launch_bounds__(256) void bias_k(const float* __restrict__ bq,
                                              const float* __restrict__ bv,
                                              const float* __restrict__ bm,
                                              const float* __restrict__ bc,
                                              const float* __restrict__ Wc,
                                              const float* __restrict__ WkT,
                                              float* __restrict__ bqk,
                                              float* __restrict__ bfull) {
    const int t = threadIdx.x;  // 256
    float a = 0.f, c = bc[t];
    for (int e = 0; e < 256; ++e) {
        a += bq[e] * WkT[e * 256 + t];
        c += bv[e] * Wc[e * 256 + t] + bm[e] * Wc[(256 + e) * 256 + t];
    }
    bqk[t] = a;
    bfull[t] = c;
}

// ---------------- Qk = id2feat[nodes] @ Wqk + bqk  (M=B, K=256, N=256) ------
__global__ __launch_bounds__(256) void qk_gemm(const float* __restrict__ id2feat,
                                               const int* __restrict__ nodes,
                                               const float* __restrict__ Wqk,
                                               const float* __restrict__ bqk,
                                               float* __restrict__ Qk) {
    __shared__ float sA[32 * 17];
    __shared__ float sB[32 * 256];
    float acc[4][4] = {};
    const int row0 = blockIdx.x * 16;
    gemm_tile<256>(id2feat, nodes, row0, 256, Wqk, acc, sA, sB);
    const int tr = threadIdx.x >> 6, tc = threadIdx.x & 63;
#pragma unroll
    for (int i = 0; i < 4; ++i) {
        float4 v = make_float4(acc[i][0] + bqk[tc * 4 + 0], acc[i][1] + bqk[tc * 4 + 1],
                               acc[i][2] + bqk[tc * 4 + 2], acc[i][3] + bqk[tc * 4 + 3]);
        *reinterpret_cast<float4*>(&Qk[(row0 + tr * 4 + i) * 256 + tc * 4]) = v;
    }
}

// ---------------- per-node: neighbor mean + attention-weighted feature sum --
// AF[b][0:256]   = sum_s softmax_s(Qk[b].feat[na[b,s]]) * feat[na[b,s]]
// AF[b][256:512] = mean_s feat[nm[b,s]]
__global__ __launch_bounds__(256) void mean_attn(const float* __restrict__ id2feat,
                                                 const int* __restrict__ neigh_mean,
                                                 const int* __restrict__ neigh_attn,
                                                 const float* __restrict__ Qk,
                                                 float* __restrict__ AF) {
    const int b = blockIdx.x;
    const int t = threadIdx.x;  // 256
    __shared__ float sS[S_NEI];
    __shared__ int sIdx[S_NEI];
    if (t < S_NEI) sIdx[t] = neigh_attn[b * S_NEI + t];

    // Phase A: mean over neigh_mean rows (thread = feature)
    float macc = 0.f;
#pragma unroll 8
    for (int s = 0; s < S_NEI; ++s) {
        const int idx = neigh_mean[b * S_NEI + s];
        macc += id2feat[idx * 256 + t];
    }
    AF[b * 512 + 256 + t] = macc * (1.0f / S_NEI);
    __syncthreads();

    // Phase B: scores. wave w handles s = w*8 .. w*8+7
    const int w = t >> 6, l = t & 63;
    const float q0 = Qk[b * 256 + l];
    const float q1 = Qk[b * 256 + 64 + l];
    const float q2 = Qk[b * 256 + 128 + l];
    const float q3 = Qk[b * 256 + 192 + l];
#pragma unroll
    for (int s8 = 0; s8 < 8; ++s8) {
        const int s = w * 8 + s8;
        const int base = sIdx[s] * 256;
        float p = q0 * id2feat[base + l] + q1 * id2feat[base + 64 + l] +
                  q2 * id2feat[base + 128 + l] + q3 * id2feat[base + 192 + l];
#pragma unroll
        for (int off = 32; off; off >>= 1) p += __shfl_xor(p, off);
        if (l == 0) sS[s] = p;
    }
    __syncthreads();

    // softmax params (computed redundantly per thread; tiny)
    float m = -1e30f;
#pragma unroll
    for (int s = 0; s < S_NEI; ++s) m = fmaxf(m, sS[s]);
    float sum = 0.f;
#pragma unroll
    for (int s = 0; s < S_NEI; ++s) sum += __expf(sS[s] - m);
    const float inv = 1.0f / sum;

    // Phase C: weighted feature sum (rows are L1/L2-hot from phase B)
    float acc = 0.f;
#pragma unroll 8
    for (int s = 0; s < S_NEI; ++s) {
        const float wgt = __expf(sS[s] - m);
        acc += wgt * id2feat[sIdx[s] * 256 + t];
    }
    AF[b * 512 + t] = acc * inv;
}

// ---------------- out = normalize(tanh(AF @ Wfused + bfull)) ----------------
__global__ __launch_bounds__(256) void final_k(const float* __restrict__ AF,
                                               const float* __restrict__ Wfused,
                                               const float* __restrict__ bfull,
                                               float* __restrict__ out) {
    __shared__ float sA[32 * 17];
    __shared__ float sB[32 * 256];
    float acc[4][4] = {};
    const int row0 = blockIdx.x * 16;
    gemm_tile<512>(AF, nullptr, row0, 512, Wfused, acc, sA, sB);
    const int tr = threadIdx.x >> 6, tc = threadIdx.x & 63;
#pragma unroll
    for (int i = 0; i < 4; ++i) {
        const float v0 = tanhf(acc[i][0] + bfull[tc * 4 + 0]);
        const float v1 = tanhf(acc[i][1] + bfull[tc * 4 + 1]);
        const float v2 = tanhf(acc[i][2] + bfull[tc * 4 + 2]);
        const float v3 = tanhf(acc[i][3] + bfull[tc * 4 + 3]);
        float p = v0 * v0 + v1 * v1 + v2 * v2 + v3 * v3;
#pragma unroll
        for (int off = 32; off; off >>= 1) p += __shfl_xor(p, off);
        const float invn = 1.0f / fmaxf(sqrtf(p), 1e-12f);
        float4 o = make_float4(v0 * invn, v1 * invn, v2 * invn, v3 * invn);
        *reinterpret_cast<float4*>(&out[(row0 + tr * 4 + i) * 256 + tc * 4]) = o;
    }
}

extern "C" void kernel_launch(void* const* d_in, const int* in_sizes, int n_in,
                              void* d_out, int out_size, void* d_ws, size_t ws_size,
                              hipStream_t stream) {
    const int* nodes      = (const int*)d_in[0];
    const int* neigh_mean = (const int*)d_in[1];
    const int* neigh_attn = (const int*)d_in[2];
    const float* id2feat  = (const float*)d_in[3];
    const float* Wm = (const float*)d_in[4];
    const float* bm = (const float*)d_in[5];
    const float* Wq = (const float*)d_in[6];
    const float* bq = (const float*)d_in[7];
    const float* Wk = (const float*)d_in[8];
    // d_in[9] = bk: cancels in softmax, unused
    const float* Wv = (const float*)d_in[10];
    const float* bv = (const float*)d_in[11];
    const float* Wc = (const float*)d_in[12];
    const float* bc = (const float*)d_in[13];
    float* out = (float*)d_out;

    const int B = in_sizes[0];  // 4096

    // workspace layout (floats)
    float* ws    = (float*)d_ws;
    float* WkT   = ws;                 // 65536
    float* Wqk   = ws + 65536;         // 65536
    float* Wvc   = ws + 131072;        // 65536  } contiguous => Wfused[512][256]
    float* Wmc   = ws + 196608;        // 65536  }
    float* bqk   = ws + 262144;        // 256
    float* bfull = ws + 262400;        // 256
    float* Qk    = ws + 262656;        // B*256
    float* AF    = ws + 262656 + B * 256;  // B*512

    transpose256<<<dim3(8, 8), dim3(32, 8), 0, stream>>>(Wk, WkT);
    precompute3<<<dim3(16, 3), 256, 0, stream>>>(Wq, Wv, Wm, Wc, WkT, Wqk, Wvc, Wmc);
    bias_k<<<1, 256, 0, stream>>>(bq, bv, bm, bc, Wc, WkT, bqk, bfull);
    qk_gemm<<<B / 16, 256, 0, stream>>>(id2feat, nodes, Wqk, bqk, Qk);
    mean_attn<<<B, 256, 0, stream>>>(id2feat, neigh_mean, neigh_attn, Qk, AF);
    final_k<<<B / 16, 256, 0, stream>>>(AF, Wvc /*Wfused*/, bfull, out);
}

// Round 2
// 122.053 us; speedup vs baseline: 1.2352x; 1.2352x over previous
//
#include <hip/hip_runtime.h>
#include <math.h>

// Problem constants (from reference): N=100000, B=4096, S=32, F=E=256
#define S_NEI 32

// ---------------- transpose 256x256 (WkT[e][f] = Wk[f][e]) ----------------
__global__ __launch_bounds__(256) void transpose256(const float* __restrict__ in,
                                                    float* __restrict__ outT) {
    __shared__ float tile[32][33];
    const int bx = blockIdx.x * 32, by = blockIdx.y * 32;
    const int x = threadIdx.x, y = threadIdx.y;  // 32 x 8
#pragma unroll
    for (int i = 0; i < 32; i += 8)
        tile[y + i][x] = in[(by + y + i) * 256 + bx + x];
    __syncthreads();
#pragma unroll
    for (int i = 0; i < 32; i += 8)
        outT[(bx + y + i) * 256 + by + x] = tile[x][y + i];
}

// ---------------- 8x256 tile GEMM (256 threads, 2x4/thread) ----------------
// C tile rows [row0, row0+8), cols [0,256). A rows optionally gathered.
// sA layout: [k][row] stride 12 (k*12+r), so a-frag is one b64 broadcast.
template <int KT>
__device__ __forceinline__ void gemm_tile(const float* __restrict__ A,
                                          const int* __restrict__ rowidx, int row0,
                                          int lda, const float* __restrict__ B,
                                          float acc[2][4], float* __restrict__ sA,
                                          float* __restrict__ sB) {
    const int t = threadIdx.x;
    const int tr = t >> 6, tc = t & 63;
    const int r = t >> 5;       // 0..7
    const int k1 = t & 31;      // 0..31
    const size_t arow = (size_t)(rowidx ? rowidx[row0 + r] : (row0 + r)) * lda;
    for (int kb = 0; kb < KT; kb += 32) {
        // A staging: 8 rows x 32 k, one scalar per thread -> sA[k][r]
        sA[k1 * 12 + r] = A[arow + kb + k1];
        // B staging: 32 rows x 256 cols, float4 per thread x 8
#pragma unroll
        for (int i = 0; i < 8; ++i) {
            *reinterpret_cast<float4*>(&sB[(i * 4 + tr) * 256 + tc * 4]) =
                *reinterpret_cast<const float4*>(&B[(size_t)(kb + i * 4 + tr) * 256 + tc * 4]);
        }
        __syncthreads();
#pragma unroll
        for (int k = 0; k < 32; ++k) {
            const float2 a2 = *reinterpret_cast<const float2*>(&sA[k * 12 + tr * 2]);
            const float4 b4 = *reinterpret_cast<const float4*>(&sB[k * 256 + tc * 4]);
            acc[0][0] += a2.x * b4.x; acc[0][1] += a2.x * b4.y;
            acc[0][2] += a2.x * b4.z; acc[0][3] += a2.x * b4.w;
            acc[1][0] += a2.y * b4.x; acc[1][1] += a2.y * b4.y;
            acc[1][2] += a2.y * b4.z; acc[1][3] += a2.y * b4.w;
        }
        __syncthreads();
    }
}

// ---------------- fused weight products: Wqk=Wq@WkT, Wvc=Wv@Wc_top, Wmc=Wm@Wc_bot
__global__ __launch_bounds__(256) void precompute3(const float* __restrict__ Wq,
                                                   const float* __restrict__ Wv,
                                                   const float* __restrict__ Wm,
                                                   const float* __restrict__ Wc,
                                                   const float* __restrict__ WkT,
                                                   float* __restrict__ Wqk,
                                                   float* __restrict__ Wvc,
                                                   float* __restrict__ Wmc) {
    __shared__ float sA[32 * 12];
    __shared__ float sB[32 * 256];
    float acc[2][4] = {};
    const float *Ap, *Bp;
    float* Cp;
    switch (blockIdx.y) {
        case 0: Ap = Wq; Bp = WkT; Cp = Wqk; break;
        case 1: Ap = Wv; Bp = Wc; Cp = Wvc; break;
        default: Ap = Wm; Bp = Wc + 256 * 256; Cp = Wmc; break;
    }
    const int row0 = blockIdx.x * 8;
    gemm_tile<256>(Ap, nullptr, row0, 256, Bp, acc, sA, sB);
    const int tr = threadIdx.x >> 6, tc = threadIdx.x & 63;
#pragma unroll
    for (int i = 0; i < 2; ++i) {
        float4 v = make_float4(acc[i][0], acc[i][1], acc[i][2], acc[i][3]);
        *reinterpret_cast<float4*>(&Cp[(row0 + tr * 2 + i) * 256 + tc * 4]) = v;
    }
}

// ---------------- fused biases: bqk = bq@WkT ; bfull = bv@Wc_top + bm@Wc_bot + bc
// one block per output column, 256-thread reduction
__global__ __launch_bounds__(256) void bias_k(const float* __restrict__ bq,
                                              const float* __restrict__ bv,
                                              const float* __restrict__ bm,
                                              const float* __restrict__ bc,
                                              const float* __restrict__ Wc,
                                              const float* __restrict__ WkT,
                                              float* __restrict__ bqk,
                                              float* __restrict__ bfull) {
    const int c = blockIdx.x;   // 256 blocks
    const int e = threadIdx.x;  // 256
    const int w = e >> 6, l = e & 63;
    float a = bq[e] * WkT[e * 256 + c];
    float v = bv[e] * Wc[e * 256 + c] + bm[e] * Wc[(256 + e) * 256 + c];
    __shared__ float redA[4], redV[4];
#pragma unroll
    for (int off = 32; off; off >>= 1) { a += __shfl_xor(a, off); v += __shfl_xor(v, off); }
    if (l == 0) { redA[w] = a; redV[w] = v; }
    __syncthreads();
    if (e == 0) {
        bqk[c] = redA[0] + redA[1] + redA[2] + redA[3];
        bfull[c] = bc[c] + redV[0] + redV[1] + redV[2] + redV[3];
    }
}

// ---------------- Qk = id2feat[nodes] @ Wqk + bqk  (M=B, K=256, N=256) ------
__global__ __launch_bounds__(256) void qk_gemm(const float* __restrict__ id2feat,
                                               const int* __restrict__ nodes,
                                               const float* __restrict__ Wqk,
                                               const float* __restrict__ bqk,
                                               float* __restrict__ Qk) {
    __shared__ float sA[32 * 12];
    __shared__ float sB[32 * 256];
    float acc[2][4] = {};
    const int row0 = blockIdx.x * 8;
    gemm_tile<256>(id2feat, nodes, row0, 256, Wqk, acc, sA, sB);
    const int tr = threadIdx.x >> 6, tc = threadIdx.x & 63;
#pragma unroll
    for (int i = 0; i < 2; ++i) {
        float4 v = make_float4(acc[i][0] + bqk[tc * 4 + 0], acc[i][1] + bqk[tc * 4 + 1],
                               acc[i][2] + bqk[tc * 4 + 2], acc[i][3] + bqk[tc * 4 + 3]);
        *reinterpret_cast<float4*>(&Qk[(row0 + tr * 2 + i) * 256 + tc * 4]) = v;
    }
}

// ---------------- per-node: neighbor mean + attention-weighted feature sum --
// AF[b][0:256]   = sum_s softmax_s(Qk[b].feat[na[b,s]]) * feat[na[b,s]]
// AF[b][256:512] = mean_s feat[nm[b,s]]
// attn rows staged ONCE in LDS (read for scores AND weighted sum)
__global__ __launch_bounds__(256) void mean_attn(const float* __restrict__ id2feat,
                                                 const int* __restrict__ neigh_mean,
                                                 const int* __restrict__ neigh_attn,
                                                 const float* __restrict__ Qk,
                                                 float* __restrict__ AF) {
    const int b = blockIdx.x;
    const int t = threadIdx.x;  // 256
    const int w = t >> 6, l = t & 63;
    __shared__ float sRows[S_NEI][256];  // 32 KB
    __shared__ float sS[S_NEI];
    __shared__ int sIdx[S_NEI];
    if (t < S_NEI) sIdx[t] = neigh_attn[b * S_NEI + t];
    __syncthreads();

    // stage attn rows: wave w handles rows w*8..w*8+7, lane l float4 at col 4l
#pragma unroll
    for (int j = 0; j < 8; ++j) {
        const int s = w * 8 + j;
        *reinterpret_cast<float4*>(&sRows[s][4 * l]) =
            *reinterpret_cast<const float4*>(&id2feat[(size_t)sIdx[s] * 256 + 4 * l]);
    }

    // mean phase (thread = feature, coalesced row reads) — overlaps staging
    float macc = 0.f;
#pragma unroll 8
    for (int s = 0; s < S_NEI; ++s) {
        const int idx = neigh_mean[b * S_NEI + s];
        macc += id2feat[(size_t)idx * 256 + t];
    }
    AF[b * 512 + 256 + t] = macc * (1.0f / S_NEI);
    __syncthreads();

    // scores from LDS: wave w handles s = w*8..w*8+7
    const float q0 = Qk[b * 256 + l];
    const float q1 = Qk[b * 256 + 64 + l];
    const float q2 = Qk[b * 256 + 128 + l];
    const float q3 = Qk[b * 256 + 192 + l];
#pragma unroll
    for (int s8 = 0; s8 < 8; ++s8) {
        const int s = w * 8 + s8;
        float p = q0 * sRows[s][l] + q1 * sRows[s][64 + l] +
                  q2 * sRows[s][128 + l] + q3 * sRows[s][192 + l];
#pragma unroll
        for (int off = 32; off; off >>= 1) p += __shfl_xor(p, off);
        if (l == 0) sS[s] = p;
    }
    __syncthreads();

    // softmax params (redundant per thread; tiny)
    float m = -1e30f;
#pragma unroll
    for (int s = 0; s < S_NEI; ++s) m = fmaxf(m, sS[s]);
    float sum = 0.f;
#pragma unroll
    for (int s = 0; s < S_NEI; ++s) sum += __expf(sS[s] - m);
    const float inv = 1.0f / sum;

    // weighted feature sum from LDS (thread = feature)
    float acc = 0.f;
#pragma unroll 8
    for (int s = 0; s < S_NEI; ++s) acc += __expf(sS[s] - m) * sRows[s][t];
    AF[b * 512 + t] = acc * inv;
}

// ---------------- out = normalize(tanh(AF @ Wfused + bfull)) ----------------
__global__ __launch_bounds__(256) void final_k(const float* __restrict__ AF,
                                               const float* __restrict__ Wfused,
                                               const float* __restrict__ bfull,
                                               float* __restrict__ out) {
    __shared__ float sA[32 * 12];
    __shared__ float sB[32 * 256];
    float acc[2][4] = {};
    const int row0 = blockIdx.x * 8;
    gemm_tile<512>(AF, nullptr, row0, 512, Wfused, acc, sA, sB);
    const int tr = threadIdx.x >> 6, tc = threadIdx.x & 63;
#pragma unroll
    for (int i = 0; i < 2; ++i) {
        const float v0 = tanhf(acc[i][0] + bfull[tc * 4 + 0]);
        const float v1 = tanhf(acc[i][1] + bfull[tc * 4 + 1]);
        const float v2 = tanhf(acc[i][2] + bfull[tc * 4 + 2]);
        const float v3 = tanhf(acc[i][3] + bfull[tc * 4 + 3]);
        float p = v0 * v0 + v1 * v1 + v2 * v2 + v3 * v3;
#pragma unroll
        for (int off = 32; off; off >>= 1) p += __shfl_xor(p, off);
        const float invn = 1.0f / fmaxf(sqrtf(p), 1e-12f);
        float4 o = make_float4(v0 * invn, v1 * invn, v2 * invn, v3 * invn);
        *reinterpret_cast<float4*>(&out[(row0 + tr * 2 + i) * 256 + tc * 4]) = o;
    }
}

extern "C" void kernel_launch(void* const* d_in, const int* in_sizes, int n_in,
                              void* d_out, int out_size, void* d_ws, size_t ws_size,
                              hipStream_t stream) {
    const int* nodes      = (const int*)d_in[0];
    const int* neigh_mean = (const int*)d_in[1];
    const int* neigh_attn = (const int*)d_in[2];
    const float* id2feat  = (const float*)d_in[3];
    const float* Wm = (const float*)d_in[4];
    const float* bm = (const float*)d_in[5];
    const float* Wq = (const float*)d_in[6];
    const float* bq = (const float*)d_in[7];
    const float* Wk = (const float*)d_in[8];
    // d_in[9] = bk: cancels in softmax, unused
    const float* Wv = (const float*)d_in[10];
    const float* bv = (const float*)d_in[11];
    const float* Wc = (const float*)d_in[12];
    const float* bc = (const float*)d_in[13];
    float* out = (float*)d_out;

    const int B = in_sizes[0];  // 4096

    // workspace layout (floats)
    float* ws    = (float*)d_ws;
    float* WkT   = ws;                 // 65536
    float* Wqk   = ws + 65536;         // 65536
    float* Wvc   = ws + 131072;        // 65536  } contiguous => Wfused[512][256]
    float* Wmc   = ws + 196608;        // 65536  }
    float* bqk   = ws + 262144;        // 256
    float* bfull = ws + 262400;        // 256
    float* Qk    = ws + 262656;        // B*256
    float* AF    = ws + 262656 + B * 256;  // B*512

    transpose256<<<dim3(8, 8), dim3(32, 8), 0, stream>>>(Wk, WkT);
    precompute3<<<dim3(32, 3), 256, 0, stream>>>(Wq, Wv, Wm, Wc, WkT, Wqk, Wvc, Wmc);
    bias_k<<<256, 256, 0, stream>>>(bq, bv, bm, bc, Wc, WkT, bqk, bfull);
    qk_gemm<<<B / 8, 256, 0, stream>>>(id2feat, nodes, Wqk, bqk, Qk);
    mean_attn<<<B, 256, 0, stream>>>(id2feat, neigh_mean, neigh_attn, Qk, AF);
    final_k<<<B / 8, 256, 0, stream>>>(AF, Wvc /*Wfused*/, bfull, out);
}